// Round 2
// baseline (2048.533 us; speedup 1.0000x reference)
//
#include <hip/hip_runtime.h>

// ---------------------------------------------------------------------------
// Qwen3VL text-attention block. IO dtype: fp32 (per reference setup_inputs).
// Internal compute: bf16 MFMA + fp32 accumulation; q/k/v/att workspace in bf16.
//   K1: fused QKV projection GEMM (fp32 A,B -> bf16 C)
//   K2: per-head RMSNorm + RoPE on q,k (bf16 data, fp32 weights/cos/sin)
//   K3: causal flash attention (vector ALU, 64x64 tiles, online softmax)
//   K4: output projection GEMM (bf16 A, fp32 B -> fp32 d_out)
// Workspace: q (2048x4096) + k (2048x1024) + v (2048x1024) + att (2048x4096)
//            bf16 = 41.9 MB.
// ---------------------------------------------------------------------------

#define S_LEN 2048
#define DIM 4096
#define NH 32
#define NKV 8
#define HD 128

typedef __attribute__((ext_vector_type(8))) short short8;
typedef __attribute__((ext_vector_type(4))) float f32x4;

__device__ __forceinline__ float bf2f(unsigned short u) {
  union { unsigned i; float f; } c; c.i = ((unsigned)u) << 16; return c.f;
}
__device__ __forceinline__ unsigned short f2bf(float f) {
  union { float f; unsigned u; } c; c.f = f;
  return (unsigned short)((c.u + 0x7fffu + ((c.u >> 16) & 1u)) >> 16);  // RNE
}
__device__ __forceinline__ float bfl(unsigned v) {
  union { unsigned i; float f; } c; c.i = v << 16; return c.f;
}
__device__ __forceinline__ float bfh(unsigned v) {
  union { unsigned i; float f; } c; c.i = v & 0xffff0000u; return c.f;
}
__device__ __forceinline__ void unpack8(uint4 v, float* f) {
  f[0] = bfl(v.x); f[1] = bfh(v.x); f[2] = bfl(v.y); f[3] = bfh(v.y);
  f[4] = bfl(v.z); f[5] = bfh(v.z); f[6] = bfl(v.w); f[7] = bfh(v.w);
}

// stage 8 contiguous elements from global into LDS as bf16 (16B store)
__device__ __forceinline__ void stage8(const float* __restrict__ g,
                                       unsigned short* l) {
  const float4 a = *(const float4*)g;
  const float4 b = *(const float4*)(g + 4);
  short8 p;
  p[0] = (short)f2bf(a.x); p[1] = (short)f2bf(a.y);
  p[2] = (short)f2bf(a.z); p[3] = (short)f2bf(a.w);
  p[4] = (short)f2bf(b.x); p[5] = (short)f2bf(b.y);
  p[6] = (short)f2bf(b.z); p[7] = (short)f2bf(b.w);
  *(short8*)l = p;
}
__device__ __forceinline__ void stage8(const unsigned short* __restrict__ g,
                                       unsigned short* l) {
  *(uint4*)l = *(const uint4*)g;
}
__device__ __forceinline__ void storeC(float* p, float v) { *p = v; }
__device__ __forceinline__ void storeC(unsigned short* p, float v) { *p = f2bf(v); }

// ---------------------------------------------------------------------------
// GEMM: C = A(MxK) @ B^T, B rows = virtual concat [Bq;Bk;Bv]
// (N 0..4095 -> Cq stride 4096, 4096..5119 -> Ck stride 1024,
//  5120..6143 -> Cv stride 1024). 128x128 tile, BK=64, 4 waves, each wave a
// 64x64 quadrant of 4x4 16x16x32 bf16 MFMAs. LDS row stride 72 shorts
// (144 B: 16B-aligned, 36-bank offset between rows -> spread conflicts).
// ---------------------------------------------------------------------------
#define LP 72

template <typename TA, typename TB, typename TC>
__global__ __launch_bounds__(256)
void gemm_bt(const TA* __restrict__ A,
             const TB* __restrict__ Bq,
             const TB* __restrict__ Bk,
             const TB* __restrict__ Bv,
             TC* __restrict__ Cq, TC* __restrict__ Ck, TC* __restrict__ Cv,
             int K) {
  __shared__ unsigned short lsA[128 * LP];
  __shared__ unsigned short lsB[128 * LP];

  const int t    = threadIdx.x;
  const int lane = t & 63;
  const int w    = t >> 6;
  const int m0   = blockIdx.y * 128;
  const int n0   = blockIdx.x * 128;

  const TB* Bp; TC* Cp; int brow0, ostride;
  if (n0 < 4096)      { Bp = Bq; Cp = Cq; brow0 = n0;        ostride = 4096; }
  else if (n0 < 5120) { Bp = Bk; Cp = Ck; brow0 = n0 - 4096; ostride = 1024; }
  else                { Bp = Bv; Cp = Cv; brow0 = n0 - 5120; ostride = 1024; }

  f32x4 acc[4][4];
#pragma unroll
  for (int a = 0; a < 4; ++a)
#pragma unroll
    for (int b = 0; b < 4; ++b)
#pragma unroll
      for (int e = 0; e < 4; ++e) acc[a][b][e] = 0.f;

  const int l15 = lane & 15;
  const int qd  = lane >> 4;
  const int wr  = w >> 1, wc = w & 1;

  const int nkb = K >> 6;
  for (int kb = 0; kb < nkb; ++kb) {
    const int k0 = kb << 6;
    // stage A-tile and B-tile (128 rows x 64 cols each), 1024 8-elem granules
#pragma unroll
    for (int c = 0; c < 4; ++c) {
      const int cI = c * 256 + t;
      const int r  = cI >> 3;
      const int c8 = (cI & 7) << 3;
      stage8(A  + (size_t)(m0 + r) * K + k0 + c8,    lsA + r * LP + c8);
      stage8(Bp + (size_t)(brow0 + r) * K + k0 + c8, lsB + r * LP + c8);
    }
    __syncthreads();

#pragma unroll
    for (int half = 0; half < 2; ++half) {
      const int kk = half * 32 + qd * 8;  // A[m=lane&15][k=quad*8+j]
      short8 af[4], bf[4];
#pragma unroll
      for (int mi = 0; mi < 4; ++mi)
        af[mi] = *(const short8*)(lsA + (wr * 64 + mi * 16 + l15) * LP + kk);
#pragma unroll
      for (int ni = 0; ni < 4; ++ni)
        bf[ni] = *(const short8*)(lsB + (wc * 64 + ni * 16 + l15) * LP + kk);
#pragma unroll
      for (int mi = 0; mi < 4; ++mi)
#pragma unroll
        for (int ni = 0; ni < 4; ++ni)
          acc[mi][ni] = __builtin_amdgcn_mfma_f32_16x16x32_bf16(
              af[mi], bf[ni], acc[mi][ni], 0, 0, 0);
    }
    __syncthreads();
  }

  // epilogue: C/D layout col=lane&15, row=quad*4+reg
#pragma unroll
  for (int mi = 0; mi < 4; ++mi)
#pragma unroll
    for (int i = 0; i < 4; ++i) {
      const int grow = m0 + wr * 64 + mi * 16 + qd * 4 + i;
#pragma unroll
      for (int ni = 0; ni < 4; ++ni) {
        const int gcol = brow0 + wc * 64 + ni * 16 + l15;
        storeC(Cp + (size_t)grow * ostride + gcol, acc[mi][ni][i]);
      }
    }
}

// ---------------------------------------------------------------------------
// RMSNorm (per head, 128 elems) + RoPE, in place on bf16 q and k.
// cos/sin/norm-weights are fp32 inputs. grid (40 heads, 2048 tokens), 128 thr.
// ---------------------------------------------------------------------------
__global__ __launch_bounds__(128)
void norm_rope(unsigned short* __restrict__ qb, unsigned short* __restrict__ kb,
               const float* __restrict__ cosb, const float* __restrict__ sinb,
               const float* __restrict__ qw, const float* __restrict__ kw) {
  const int hIdx = blockIdx.x;
  const int s    = blockIdx.y;
  const int d    = threadIdx.x;

  unsigned short* p; const float* wt;
  if (hIdx < NH) { p = qb + (size_t)s * (NH * HD) + hIdx * HD + d; wt = qw; }
  else           { p = kb + (size_t)s * (NKV * HD) + (hIdx - NH) * HD + d; wt = kw; }

  const float v = bf2f(*p);
  float ss = v * v;
  for (int off = 32; off; off >>= 1) ss += __shfl_down(ss, off);
  __shared__ float red[2];
  __shared__ float xs[128];
  if ((d & 63) == 0) red[d >> 6] = ss;
  __syncthreads();
  const float tot = red[0] + red[1];
  const float r   = rsqrtf(tot * (1.f / 128.f) + 1e-6f);
  const float xn  = v * r * wt[d];
  xs[d] = xn;
  __syncthreads();
  const float rot = (d < 64) ? -xs[d + 64] : xs[d - 64];
  const float o   = xn * cosb[s * HD + d] + rot * sinb[s * HD + d];
  *p = f2bf(o);
}

// ---------------------------------------------------------------------------
// Causal flash attention, vector ALU, bf16 q/k/v/att. Block = 256 threads per
// (head, 64 q-rows); loops over 64-key tiles with online softmax.
// ---------------------------------------------------------------------------
#define QPAD 136
#define SPAD 65

__global__ __launch_bounds__(256)
void attn_kernel(const unsigned short* __restrict__ qB,
                 const unsigned short* __restrict__ kB,
                 const unsigned short* __restrict__ vB,
                 unsigned short* __restrict__ oB) {
  __shared__ unsigned short qs[64 * QPAD];
  __shared__ unsigned short ks[64 * QPAD];
  __shared__ unsigned short vs[64 * QPAD];
  __shared__ float Ssh[64 * SPAD];
  __shared__ float mrow[64], lrow[64], arow[64];

  const int t   = threadIdx.x;
  const int qt  = (gridDim.x - 1) - blockIdx.x;  // heavy tiles dispatch first
  const int h   = blockIdx.y;
  const int kvh = h >> 2;

  {  // stage q-tile (64 x 128)
    const size_t base = (size_t)(qt * 64) * (NH * HD) + h * HD;
    for (int cI = t; cI < 1024; cI += 256) {
      const int r = cI >> 4, c8 = (cI & 15) << 3;
      *(uint4*)&qs[r * QPAD + c8] =
          *(const uint4*)&qB[base + (size_t)r * (NH * HD) + c8];
    }
  }
  if (t < 64) { mrow[t] = -1e30f; lrow[t] = 0.f; }
  float O[32];
#pragma unroll
  for (int i = 0; i < 32; ++i) O[i] = 0.f;

  const int tr = t >> 4, tc = t & 15;          // score phase mapping
  const int rown = t >> 2, db = (t & 3) << 5;  // PV phase mapping
  __syncthreads();

  for (int kt = 0; kt <= qt; ++kt) {
    const size_t kbase = (size_t)(kt * 64) * (NKV * HD) + kvh * HD;
    for (int cI = t; cI < 1024; cI += 256) {
      const int r = cI >> 4, c8 = (cI & 15) << 3;
      *(uint4*)&ks[r * QPAD + c8] =
          *(const uint4*)&kB[kbase + (size_t)r * (NKV * HD) + c8];
      *(uint4*)&vs[r * QPAD + c8] =
          *(const uint4*)&vB[kbase + (size_t)r * (NKV * HD) + c8];
    }
    __syncthreads();

    float sc[4][4];
#pragma unroll
    for (int i = 0; i < 4; ++i)
#pragma unroll
      for (int j = 0; j < 4; ++j) sc[i][j] = 0.f;

    for (int k8 = 0; k8 < 16; ++k8) {
      uint4 qa[4], ka[4];
      float qf[4][8], kf[4][8];
#pragma unroll
      for (int i = 0; i < 4; ++i) {
        qa[i] = *(const uint4*)&qs[(tr + 16 * i) * QPAD + k8 * 8];
        ka[i] = *(const uint4*)&ks[(tc + 16 * i) * QPAD + k8 * 8];
      }
#pragma unroll
      for (int i = 0; i < 4; ++i) { unpack8(qa[i], qf[i]); unpack8(ka[i], kf[i]); }
#pragma unroll
      for (int i = 0; i < 4; ++i)
#pragma unroll
        for (int j = 0; j < 4; ++j)
#pragma unroll
          for (int e = 0; e < 8; ++e) sc[i][j] += qf[i][e] * kf[j][e];
    }

    const float scale = 0.08838834764831845f;  // 1/sqrt(128)
#pragma unroll
    for (int i = 0; i < 4; ++i)
#pragma unroll
      for (int j = 0; j < 4; ++j) {
        const int r = tr + 16 * i, c = tc + 16 * j;
        float val = sc[i][j] * scale;
        if (kt * 64 + c > qt * 64 + r) val = -1e30f;  // causal mask
        Ssh[r * SPAD + c] = val;
      }
    __syncthreads();

    if (t < 64) {  // online softmax per row
      const int r = t;
      const float mo = mrow[r];
      float mx = mo;
      for (int c = 0; c < 64; ++c) mx = fmaxf(mx, Ssh[r * SPAD + c]);
      const float al = __expf(mo - mx);
      float sum = 0.f;
      for (int c = 0; c < 64; ++c) {
        const float p = __expf(Ssh[r * SPAD + c] - mx);
        Ssh[r * SPAD + c] = p;
        sum += p;
      }
      mrow[r] = mx;
      lrow[r] = lrow[r] * al + sum;
      arow[r] = al;
    }
    __syncthreads();

    {  // PV accumulate: thread owns (row, 32 dims)
      const float al = arow[rown];
#pragma unroll
      for (int i = 0; i < 32; ++i) O[i] *= al;
      for (int j = 0; j < 64; ++j) {
        const float p = Ssh[rown * SPAD + j];
#pragma unroll
        for (int i8 = 0; i8 < 4; ++i8) {
          const uint4 vv = *(const uint4*)&vs[j * QPAD + db + i8 * 8];
          float vf[8];
          unpack8(vv, vf);
#pragma unroll
          for (int e = 0; e < 8; ++e) O[i8 * 8 + e] += p * vf[e];
        }
      }
    }
    __syncthreads();
  }

  const float linv = 1.f / lrow[rown];
  const size_t ob = (size_t)(qt * 64 + rown) * (NH * HD) + h * HD + db;
#pragma unroll
  for (int i = 0; i < 32; ++i) oB[ob + i] = f2bf(O[i] * linv);
}

// ---------------------------------------------------------------------------
extern "C" void kernel_launch(void* const* d_in, const int* in_sizes, int n_in,
                              void* d_out, int out_size, void* d_ws, size_t ws_size,
                              hipStream_t stream) {
  const float* x    = (const float*)d_in[0];
  const float* cosb = (const float*)d_in[1];
  const float* sinb = (const float*)d_in[2];
  const float* wq   = (const float*)d_in[3];
  const float* wk   = (const float*)d_in[4];
  const float* wv   = (const float*)d_in[5];
  const float* wo   = (const float*)d_in[6];
  const float* qnw  = (const float*)d_in[7];
  const float* knw  = (const float*)d_in[8];

  unsigned short* q   = (unsigned short*)d_ws;        // 2048*4096 bf16
  unsigned short* k   = q + (size_t)S_LEN * DIM;      // 2048*1024
  unsigned short* v   = k + (size_t)S_LEN * NKV * HD; // 2048*1024
  unsigned short* att = v + (size_t)S_LEN * NKV * HD; // 2048*4096

  // 1) QKV projection: N = 4096+1024+1024 = 6144 -> 48 col tiles
  gemm_bt<float, float, unsigned short>
      <<<dim3(48, 16), dim3(256), 0, stream>>>(x, wq, wk, wv, q, k, v, DIM);
  // 2) RMSNorm + RoPE (32 q heads + 8 k heads per token)
  norm_rope<<<dim3(NH + NKV, S_LEN), dim3(128), 0, stream>>>(q, k, cosb, sinb,
                                                             qnw, knw);
  // 3) causal attention
  attn_kernel<<<dim3(S_LEN / 64, NH), dim3(256), 0, stream>>>(q, k, v, att);
  // 4) output projection: N = 4096 -> 32 col tiles (k/v paths never taken)
  gemm_bt<unsigned short, float, float>
      <<<dim3(32, 16), dim3(256), 0, stream>>>(att, wo, wo, wo, (float*)d_out,
                                               nullptr, nullptr, DIM);
}

// Round 3
// 879.966 us; speedup vs baseline: 2.3280x; 2.3280x over previous
//
#include <hip/hip_runtime.h>

// ---------------------------------------------------------------------------
// Qwen3VL text-attention block. IO fp32; internal bf16 MFMA + fp32 accum.
//   K1: fused QKV projection GEMM (fp32 A,B -> bf16 q,k; V written TRANSPOSED)
//   K2: per-head RMSNorm + RoPE on q,k
//   K3: causal flash attention, MFMA QK^T + PV, online softmax in C-layout regs
//   K4: output projection GEMM (bf16 A, fp32 B -> fp32 d_out)
// Workspace (bf16): q 2048x4096 | k 2048x1024 | vT 1024x2048 | att 2048x4096
//                   = 20,971,520 shorts = 41.9 MB (same as round 2).
// ---------------------------------------------------------------------------

#define S_LEN 2048
#define DIM 4096
#define NH 32
#define NKV 8
#define HD 128

typedef __attribute__((ext_vector_type(8))) short short8;
typedef __attribute__((ext_vector_type(4))) float f32x4;

__device__ __forceinline__ float bf2f(unsigned short u) {
  union { unsigned i; float f; } c; c.i = ((unsigned)u) << 16; return c.f;
}
__device__ __forceinline__ unsigned short f2bf(float f) {
  union { float f; unsigned u; } c; c.f = f;
  return (unsigned short)((c.u + 0x7fffu + ((c.u >> 16) & 1u)) >> 16);  // RNE
}

// stage 8 contiguous elems from global into LDS as bf16 (16B store)
__device__ __forceinline__ void stage8(const float* __restrict__ g,
                                       unsigned short* l) {
  const float4 a = *(const float4*)g;
  const float4 b = *(const float4*)(g + 4);
  short8 p;
  p[0] = (short)f2bf(a.x); p[1] = (short)f2bf(a.y);
  p[2] = (short)f2bf(a.z); p[3] = (short)f2bf(a.w);
  p[4] = (short)f2bf(b.x); p[5] = (short)f2bf(b.y);
  p[6] = (short)f2bf(b.z); p[7] = (short)f2bf(b.w);
  *(short8*)l = p;
}
__device__ __forceinline__ void stage8(const unsigned short* __restrict__ g,
                                       unsigned short* l) {
  *(uint4*)l = *(const uint4*)g;
}
__device__ __forceinline__ void storeC(float* p, float v) { *p = v; }
__device__ __forceinline__ void storeC(unsigned short* p, float v) { *p = f2bf(v); }

// ---------------------------------------------------------------------------
// GEMM: C = A(MxK) @ B^T, B rows = virtual concat [Bq;Bk;Bv].
// N 0..4095 -> Cq (stride 4096), 4096..5119 -> Ck (stride 1024),
// 5120..6143 -> Cv. If vtrans, the V segment stores transposed:
// Cv[gcol * S_LEN + grow]  (i.e. vT[d][token]).
// 128x128 tile, BK=64, 4 waves, 4x4 16x16x32 bf16 MFMAs per wave.
// ---------------------------------------------------------------------------
#define LP 72

template <typename TA, typename TB, typename TC>
__global__ __launch_bounds__(256)
void gemm_bt(const TA* __restrict__ A,
             const TB* __restrict__ Bq,
             const TB* __restrict__ Bk,
             const TB* __restrict__ Bv,
             TC* __restrict__ Cq, TC* __restrict__ Ck, TC* __restrict__ Cv,
             int K, int vtrans) {
  __shared__ unsigned short lsA[128 * LP];
  __shared__ unsigned short lsB[128 * LP];

  const int t    = threadIdx.x;
  const int lane = t & 63;
  const int w    = t >> 6;
  const int m0   = blockIdx.y * 128;
  const int n0   = blockIdx.x * 128;

  const TB* Bp; TC* Cp; int brow0, ostride, vtr;
  if (n0 < 4096)      { Bp = Bq; Cp = Cq; brow0 = n0;        ostride = 4096; vtr = 0; }
  else if (n0 < 5120) { Bp = Bk; Cp = Ck; brow0 = n0 - 4096; ostride = 1024; vtr = 0; }
  else                { Bp = Bv; Cp = Cv; brow0 = n0 - 5120; ostride = 1024; vtr = vtrans; }

  f32x4 acc[4][4];
#pragma unroll
  for (int a = 0; a < 4; ++a)
#pragma unroll
    for (int b = 0; b < 4; ++b)
#pragma unroll
      for (int e = 0; e < 4; ++e) acc[a][b][e] = 0.f;

  const int l15 = lane & 15;
  const int qd  = lane >> 4;
  const int wr  = w >> 1, wc = w & 1;

  const int nkb = K >> 6;
  for (int kb = 0; kb < nkb; ++kb) {
    const int k0 = kb << 6;
#pragma unroll
    for (int c = 0; c < 4; ++c) {
      const int cI = c * 256 + t;
      const int r  = cI >> 3;
      const int c8 = (cI & 7) << 3;
      stage8(A  + (size_t)(m0 + r) * K + k0 + c8,    lsA + r * LP + c8);
      stage8(Bp + (size_t)(brow0 + r) * K + k0 + c8, lsB + r * LP + c8);
    }
    __syncthreads();

#pragma unroll
    for (int half = 0; half < 2; ++half) {
      const int kk = half * 32 + qd * 8;  // A[m=lane&15][k=quad*8+j]
      short8 af[4], bf[4];
#pragma unroll
      for (int mi = 0; mi < 4; ++mi)
        af[mi] = *(const short8*)(lsA + (wr * 64 + mi * 16 + l15) * LP + kk);
#pragma unroll
      for (int ni = 0; ni < 4; ++ni)
        bf[ni] = *(const short8*)(lsB + (wc * 64 + ni * 16 + l15) * LP + kk);
#pragma unroll
      for (int mi = 0; mi < 4; ++mi)
#pragma unroll
        for (int ni = 0; ni < 4; ++ni)
          acc[mi][ni] = __builtin_amdgcn_mfma_f32_16x16x32_bf16(
              af[mi], bf[ni], acc[mi][ni], 0, 0, 0);
    }
    __syncthreads();
  }

  // epilogue: C/D layout col=lane&15, row=quad*4+reg
#pragma unroll
  for (int mi = 0; mi < 4; ++mi)
#pragma unroll
    for (int i = 0; i < 4; ++i) {
      const int grow = m0 + wr * 64 + mi * 16 + qd * 4 + i;
#pragma unroll
      for (int ni = 0; ni < 4; ++ni) {
        const int gcol = brow0 + wc * 64 + ni * 16 + l15;
        if (vtr)
          storeC(Cp + (size_t)gcol * S_LEN + grow, acc[mi][ni][i]);
        else
          storeC(Cp + (size_t)grow * ostride + gcol, acc[mi][ni][i]);
      }
    }
}

// ---------------------------------------------------------------------------
// RMSNorm (per head, 128 elems) + RoPE, in place on bf16 q and k.
// ---------------------------------------------------------------------------
__global__ __launch_bounds__(128)
void norm_rope(unsigned short* __restrict__ qb, unsigned short* __restrict__ kb,
               const float* __restrict__ cosb, const float* __restrict__ sinb,
               const float* __restrict__ qw, const float* __restrict__ kw) {
  const int hIdx = blockIdx.x;
  const int s    = blockIdx.y;
  const int d    = threadIdx.x;

  unsigned short* p; const float* wt;
  if (hIdx < NH) { p = qb + (size_t)s * (NH * HD) + hIdx * HD + d; wt = qw; }
  else           { p = kb + (size_t)s * (NKV * HD) + (hIdx - NH) * HD + d; wt = kw; }

  const float v = bf2f(*p);
  float ss = v * v;
  for (int off = 32; off; off >>= 1) ss += __shfl_down(ss, off);
  __shared__ float red[2];
  __shared__ float xs[128];
  if ((d & 63) == 0) red[d >> 6] = ss;
  __syncthreads();
  const float tot = red[0] + red[1];
  const float r   = rsqrtf(tot * (1.f / 128.f) + 1e-6f);
  const float xn  = v * r * wt[d];
  xs[d] = xn;
  __syncthreads();
  const float rot = (d < 64) ? -xs[d + 64] : xs[d - 64];
  const float o   = xn * cosb[s * HD + d] + rot * sinb[s * HD + d];
  *p = f2bf(o);
}

// ---------------------------------------------------------------------------
// Causal flash attention with MFMA. Block = 256 thr = 4 waves; block handles
// (head, 64 q-rows); each wave 16 q-rows. K-tile (64x128) and V^T-tile
// (128x64) staged dense via global_load_lds(16B). Q A-frags preloaded to
// registers. Online softmax in MFMA C-layout registers (shfl_xor over the
// 16-lane column group). P -> per-wave padded LDS -> PV A-operand.
// LDS: 16K + 16K + 9K = 41.2 KB -> 3 blocks/CU.
// ---------------------------------------------------------------------------
#define PSTR 72  // P row stride (shorts); 144 B = 16B-aligned, odd dword tilt

__global__ __launch_bounds__(256)
void attn_mfma(const unsigned short* __restrict__ qB,
               const unsigned short* __restrict__ kB,
               const unsigned short* __restrict__ vT,
               unsigned short* __restrict__ oB) {
  __shared__ unsigned short ks[64 * 128];   // [key][d] dense
  __shared__ unsigned short vt[128 * 64];   // [d][key] dense
  __shared__ unsigned short Ps[4 * 16 * PSTR];

  const int t    = threadIdx.x;
  const int lane = t & 63;
  const int w    = t >> 6;
  const int qt   = (gridDim.x - 1) - blockIdx.x;  // heavy tiles first
  const int h    = blockIdx.y;
  const int kvh  = h >> 2;
  const int l15  = lane & 15;
  const int qd   = lane >> 4;

  // preload Q A-fragments: rows qt*64 + w*16 + l15, k = step*32 + qd*8 + j
  short8 qf[4];
  {
    const unsigned short* qp =
        qB + (size_t)(qt * 64 + w * 16 + l15) * (NH * HD) + h * HD + qd * 8;
#pragma unroll
    for (int s = 0; s < 4; ++s) qf[s] = *(const short8*)(qp + s * 32);
  }

  f32x4 O[8];
#pragma unroll
  for (int nt = 0; nt < 8; ++nt)
#pragma unroll
    for (int e = 0; e < 4; ++e) O[nt][e] = 0.f;
  float m_i[4] = {-1e30f, -1e30f, -1e30f, -1e30f};
  float l_i[4] = {0.f, 0.f, 0.f, 0.f};

  unsigned short* Pw = Ps + w * (16 * PSTR);
  const float scale = 0.08838834764831845f;  // 1/sqrt(128)

  for (int kt = 0; kt <= qt; ++kt) {
    // ---- stage K-tile: 16 chunks of 1 KB (4 keys each); wave w -> 4 chunks
#pragma unroll
    for (int c = 0; c < 4; ++c) {
      const int chunk = w * 4 + c;
      const int krow  = chunk * 4 + (lane >> 4);
      const unsigned short* g = kB + (size_t)(kt * 64 + krow) * (NKV * HD) +
                                kvh * HD + (lane & 15) * 8;
      __builtin_amdgcn_global_load_lds(
          (const __attribute__((address_space(1))) void*)g,
          (__attribute__((address_space(3))) void*)(ks + chunk * 512), 16, 0, 0);
    }
    // ---- stage V^T-tile: 16 chunks (8 d-rows each)
#pragma unroll
    for (int c = 0; c < 4; ++c) {
      const int chunk = w * 4 + c;
      const int drow  = chunk * 8 + (lane >> 3);
      const unsigned short* g = vT + (size_t)(kvh * HD + drow) * S_LEN +
                                kt * 64 + (lane & 7) * 8;
      __builtin_amdgcn_global_load_lds(
          (const __attribute__((address_space(1))) void*)g,
          (__attribute__((address_space(3))) void*)(vt + chunk * 512), 16, 0, 0);
    }
    asm volatile("s_waitcnt vmcnt(0)" ::: "memory");
    __syncthreads();

    // ---- QK^T: S[ct] = 16 q-rows x 16 keys, ct = key tile
    f32x4 S[4];
#pragma unroll
    for (int ct = 0; ct < 4; ++ct) {
#pragma unroll
      for (int e = 0; e < 4; ++e) S[ct][e] = 0.f;
#pragma unroll
      for (int s = 0; s < 4; ++s) {
        const short8 kf =
            *(const short8*)(ks + (ct * 16 + l15) * 128 + s * 32 + qd * 8);
        S[ct] = __builtin_amdgcn_mfma_f32_16x16x32_bf16(qf[s], kf, S[ct], 0, 0, 0);
      }
    }

    // ---- scale + causal mask (diagonal tile only; wave-uniform branch)
    if (kt == qt) {
#pragma unroll
      for (int ct = 0; ct < 4; ++ct)
#pragma unroll
        for (int i = 0; i < 4; ++i) {
          const int rloc = w * 16 + qd * 4 + i;   // row within 64-block
          const int cloc = ct * 16 + l15;         // col within 64-block
          S[ct][i] = (cloc > rloc) ? -1e30f : S[ct][i] * scale;
        }
    } else {
#pragma unroll
      for (int ct = 0; ct < 4; ++ct)
#pragma unroll
        for (int i = 0; i < 4; ++i) S[ct][i] *= scale;
    }

    // ---- online softmax in C-layout registers
    float alpha[4];
#pragma unroll
    for (int i = 0; i < 4; ++i) {
      float mx = fmaxf(fmaxf(S[0][i], S[1][i]), fmaxf(S[2][i], S[3][i]));
#pragma unroll
      for (int off = 1; off < 16; off <<= 1)
        mx = fmaxf(mx, __shfl_xor(mx, off));
      const float mnew = fmaxf(m_i[i], mx);
      alpha[i] = __expf(m_i[i] - mnew);
      m_i[i]   = mnew;
      float sum = 0.f;
#pragma unroll
      for (int ct = 0; ct < 4; ++ct) {
        S[ct][i] = __expf(S[ct][i] - mnew);
        sum += S[ct][i];
      }
#pragma unroll
      for (int off = 1; off < 16; off <<= 1) sum += __shfl_xor(sum, off);
      l_i[i] = l_i[i] * alpha[i] + sum;
    }

    // ---- write P (bf16) to per-wave LDS in A-operand source layout
#pragma unroll
    for (int ct = 0; ct < 4; ++ct)
#pragma unroll
      for (int i = 0; i < 4; ++i)
        Pw[(qd * 4 + i) * PSTR + ct * 16 + l15] = f2bf(S[ct][i]);

    // ---- rescale O
#pragma unroll
    for (int nt = 0; nt < 8; ++nt)
#pragma unroll
      for (int i = 0; i < 4; ++i) O[nt][i] *= alpha[i];

    // ---- PV: O += P(16x64) * V(64x128); A=P frags, B=V^T frags
    {
      short8 pf0 = *(const short8*)(Pw + l15 * PSTR + qd * 8);
      short8 pf1 = *(const short8*)(Pw + l15 * PSTR + 32 + qd * 8);
#pragma unroll
      for (int nt = 0; nt < 8; ++nt) {
        const short8 vf0 =
            *(const short8*)(vt + (nt * 16 + l15) * 64 + qd * 8);
        O[nt] = __builtin_amdgcn_mfma_f32_16x16x32_bf16(pf0, vf0, O[nt], 0, 0, 0);
        const short8 vf1 =
            *(const short8*)(vt + (nt * 16 + l15) * 64 + 32 + qd * 8);
        O[nt] = __builtin_amdgcn_mfma_f32_16x16x32_bf16(pf1, vf1, O[nt], 0, 0, 0);
      }
    }
    __syncthreads();  // protect ks/vt before next tile's staging
  }

  // ---- epilogue: O /= l, store C-layout (col=l15, row=qd*4+i)
  float linv[4];
#pragma unroll
  for (int i = 0; i < 4; ++i) linv[i] = 1.f / l_i[i];
#pragma unroll
  for (int nt = 0; nt < 8; ++nt)
#pragma unroll
    for (int i = 0; i < 4; ++i) {
      const size_t row = (size_t)(qt * 64 + w * 16 + qd * 4 + i);
      oB[row * (NH * HD) + h * HD + nt * 16 + l15] = f2bf(O[nt][i] * linv[i]);
    }
}

// ---------------------------------------------------------------------------
extern "C" void kernel_launch(void* const* d_in, const int* in_sizes, int n_in,
                              void* d_out, int out_size, void* d_ws, size_t ws_size,
                              hipStream_t stream) {
  const float* x    = (const float*)d_in[0];
  const float* cosb = (const float*)d_in[1];
  const float* sinb = (const float*)d_in[2];
  const float* wq   = (const float*)d_in[3];
  const float* wk   = (const float*)d_in[4];
  const float* wv   = (const float*)d_in[5];
  const float* wo   = (const float*)d_in[6];
  const float* qnw  = (const float*)d_in[7];
  const float* knw  = (const float*)d_in[8];

  unsigned short* q   = (unsigned short*)d_ws;         // 2048*4096 bf16
  unsigned short* k   = q + (size_t)S_LEN * DIM;       // 2048*1024
  unsigned short* vT  = k + (size_t)S_LEN * NKV * HD;  // 1024*2048 (transposed)
  unsigned short* att = vT + (size_t)NKV * HD * S_LEN; // 2048*4096

  // 1) QKV projection (V stored transposed): N = 6144 -> 48 col tiles
  gemm_bt<float, float, unsigned short>
      <<<dim3(48, 16), dim3(256), 0, stream>>>(x, wq, wk, wv, q, k, vT, DIM, 1);
  // 2) RMSNorm + RoPE on q (32 heads) and k (8 heads)
  norm_rope<<<dim3(NH + NKV, S_LEN), dim3(128), 0, stream>>>(q, k, cosb, sinb,
                                                             qnw, knw);
  // 3) causal MFMA attention
  attn_mfma<<<dim3(S_LEN / 64, NH), dim3(256), 0, stream>>>(q, k, vT, att);
  // 4) output projection: N = 4096 -> 32 col tiles
  gemm_bt<unsigned short, float, float>
      <<<dim3(32, 16), dim3(256), 0, stream>>>(att, wo, wo, wo, (float*)d_out,
                                               nullptr, nullptr, DIM, 0);
}

// Round 4
// 758.404 us; speedup vs baseline: 2.7011x; 1.1603x over previous
//
#include <hip/hip_runtime.h>

// ---------------------------------------------------------------------------
// Qwen3VL text-attention block. IO fp32; internal bf16 MFMA + fp32 accum.
//   K0: fp32 -> bf16 streaming convert of x, [wq;wk;wv], wo (once per launch)
//   K1: fused QKV projection GEMM (bf16, m97 global_load_lds structure;
//       V written TRANSPOSED for the attention PV B-operand)
//   K2: per-head RMSNorm + RoPE on q,k (softmax scale folded into q)
//   K3: causal flash attention, MFMA QK^T + PV, fixed-max online softmax
//   K4: output projection GEMM (bf16 A/B -> fp32 d_out)
// Workspace (shorts): q 2048x4096 | k 2048x1024 | vT 1024x2048 | att 2048x4096
//   | xb 2048x4096 | wqkvb 6144x4096 | wob 4096x4096  = 142.6 MB.
// ---------------------------------------------------------------------------

#define S_LEN 2048
#define DIM 4096
#define NH 32
#define NKV 8
#define HD 128
#define SCALE 0.08838834764831845f  // 1/sqrt(128)

typedef __attribute__((ext_vector_type(8))) short short8;
typedef __attribute__((ext_vector_type(4))) float f32x4;

__device__ __forceinline__ float bf2f(unsigned short u) {
  union { unsigned i; float f; } c; c.i = ((unsigned)u) << 16; return c.f;
}
__device__ __forceinline__ unsigned short f2bf(float f) {
  union { float f; unsigned u; } c; c.f = f;
  return (unsigned short)((c.u + 0x7fffu + ((c.u >> 16) & 1u)) >> 16);  // RNE
}
__device__ __forceinline__ void cvt8(const float* __restrict__ g,
                                     unsigned short* __restrict__ d) {
  const float4 a = *(const float4*)g;
  const float4 b = *(const float4*)(g + 4);
  short8 p;
  p[0] = (short)f2bf(a.x); p[1] = (short)f2bf(a.y);
  p[2] = (short)f2bf(a.z); p[3] = (short)f2bf(a.w);
  p[4] = (short)f2bf(b.x); p[5] = (short)f2bf(b.y);
  p[6] = (short)f2bf(b.z); p[7] = (short)f2bf(b.w);
  *(short8*)d = p;
}
__device__ __forceinline__ void storeC(float* p, float v) { *p = v; }
__device__ __forceinline__ void storeC(unsigned short* p, float v) { *p = f2bf(v); }

// ---------------------------------------------------------------------------
// K0: fp32 -> bf16 convert. One thread per 8-elem granule, exact grid.
// Segments (granules): x 1048576 | wq 2097152 | wk 524288 | wv 524288
//                      | wo 2097152  -> total 6291456 = 24576 blocks x 256.
// ---------------------------------------------------------------------------
#define G_X   1048576u
#define G_WQ  2097152u
#define G_WK   524288u
#define G_WV   524288u
#define G_QKV (G_WQ + G_WK + G_WV)

__global__ __launch_bounds__(256)
void cvt_all(const float* __restrict__ x,  const float* __restrict__ wq,
             const float* __restrict__ wk, const float* __restrict__ wv,
             const float* __restrict__ wo,
             unsigned short* __restrict__ xb,
             unsigned short* __restrict__ wqkvb,
             unsigned short* __restrict__ wob) {
  const size_t g = (size_t)blockIdx.x * 256 + threadIdx.x;
  if (g < G_X) {
    cvt8(x + g * 8, xb + g * 8);
  } else if (g < G_X + G_QKV) {
    const size_t o = g - G_X;
    const float* s = (o < G_WQ) ? wq + o * 8
                   : (o < G_WQ + G_WK) ? wk + (o - G_WQ) * 8
                                       : wv + (o - G_WQ - G_WK) * 8;
    cvt8(s, wqkvb + o * 8);
  } else {
    const size_t o = g - (G_X + G_QKV);
    cvt8(wo + o * 8, wob + o * 8);
  }
}

// ---------------------------------------------------------------------------
// K1/K4: bf16 GEMM, C = A(MxK) @ B^T. m97 structure: 128x128 tile, BK=64,
// dense LDS, global_load_lds width-16 staging, 4 waves x (4x4) 16x16x32 MFMA.
// QKV=1: B rows are [wq;wk;wv]; col segment 0..4095 -> q (stride 4096),
//   4096..5119 -> k (stride 1024), 5120..6143 -> vT stored TRANSPOSED
//   (vT[d][token]). QKV=0: single fp32 C, stride 4096.
// ---------------------------------------------------------------------------
template <int QKV, typename TC>
__global__ __launch_bounds__(256)
void gemm16(const unsigned short* __restrict__ A,
            const unsigned short* __restrict__ B,
            TC* __restrict__ C0,
            unsigned short* __restrict__ Ck,
            unsigned short* __restrict__ Cv, int K) {
  __shared__ unsigned short lsA[128 * 64];
  __shared__ unsigned short lsB[128 * 64];

  const int t    = threadIdx.x;
  const int lane = t & 63;
  const int w    = t >> 6;
  const int m0   = blockIdx.y * 128;
  const int n0   = blockIdx.x * 128;

  f32x4 acc[4][4];
#pragma unroll
  for (int a = 0; a < 4; ++a)
#pragma unroll
    for (int b = 0; b < 4; ++b)
#pragma unroll
      for (int e = 0; e < 4; ++e) acc[a][b][e] = 0.f;

  const int l15 = lane & 15;
  const int qd  = lane >> 4;
  const int wr  = w >> 1, wc = w & 1;
  const int srow = lane >> 3;       // staging row within 8-row chunk
  const int scol = (lane & 7) * 8;  // staging col (16B granule)

  const int nkb = K >> 6;
  for (int kb = 0; kb < nkb; ++kb) {
    const int k0 = kb << 6;
#pragma unroll
    for (int c = 0; c < 4; ++c) {
      const int chunk = c * 4 + w;         // wave-uniform
      const int row   = chunk * 8 + srow;
      const unsigned short* ga = A + (size_t)(m0 + row) * K + k0 + scol;
      const unsigned short* gb = B + (size_t)(n0 + row) * K + k0 + scol;
      __builtin_amdgcn_global_load_lds(
          (const __attribute__((address_space(1))) void*)ga,
          (__attribute__((address_space(3))) void*)(lsA + chunk * 512), 16, 0, 0);
      __builtin_amdgcn_global_load_lds(
          (const __attribute__((address_space(1))) void*)gb,
          (__attribute__((address_space(3))) void*)(lsB + chunk * 512), 16, 0, 0);
    }
    asm volatile("s_waitcnt vmcnt(0)" ::: "memory");
    __syncthreads();

#pragma unroll
    for (int half = 0; half < 2; ++half) {
      const int kk = half * 32 + qd * 8;  // A[m=lane&15][k=quad*8+j]
      short8 af[4], bf[4];
#pragma unroll
      for (int mi = 0; mi < 4; ++mi)
        af[mi] = *(const short8*)(lsA + (wr * 64 + mi * 16 + l15) * 64 + kk);
#pragma unroll
      for (int ni = 0; ni < 4; ++ni)
        bf[ni] = *(const short8*)(lsB + (wc * 64 + ni * 16 + l15) * 64 + kk);
#pragma unroll
      for (int mi = 0; mi < 4; ++mi)
#pragma unroll
        for (int ni = 0; ni < 4; ++ni)
          acc[mi][ni] = __builtin_amdgcn_mfma_f32_16x16x32_bf16(
              af[mi], bf[ni], acc[mi][ni], 0, 0, 0);
    }
    __syncthreads();
  }

  // epilogue: C/D layout col=lane&15, row=quad*4+reg
#pragma unroll
  for (int mi = 0; mi < 4; ++mi)
#pragma unroll
    for (int i = 0; i < 4; ++i) {
      const int grow = m0 + wr * 64 + mi * 16 + qd * 4 + i;
#pragma unroll
      for (int ni = 0; ni < 4; ++ni) {
        const int gcol = n0 + wc * 64 + ni * 16 + l15;
        if (QKV) {
          if (n0 < 4096)
            storeC((unsigned short*)C0 + (size_t)grow * 4096 + gcol,
                   acc[mi][ni][i]);
          else if (n0 < 5120)
            Ck[(size_t)grow * 1024 + (gcol - 4096)] = f2bf(acc[mi][ni][i]);
          else  // V transposed: vT[d][token]
            Cv[(size_t)(gcol - 5120) * S_LEN + grow] = f2bf(acc[mi][ni][i]);
        } else {
          storeC(C0 + (size_t)grow * 4096 + gcol, acc[mi][ni][i]);
        }
      }
    }
}

// ---------------------------------------------------------------------------
// K2: RMSNorm (per head, 128 elems) + RoPE, in place on bf16 q and k.
// Softmax scale folded into q output.
// ---------------------------------------------------------------------------
__global__ __launch_bounds__(128)
void norm_rope(unsigned short* __restrict__ qb, unsigned short* __restrict__ kb,
               const float* __restrict__ cosb, const float* __restrict__ sinb,
               const float* __restrict__ qw, const float* __restrict__ kw) {
  const int hIdx = blockIdx.x;
  const int s    = blockIdx.y;
  const int d    = threadIdx.x;

  unsigned short* p; const float* wt;
  if (hIdx < NH) { p = qb + (size_t)s * (NH * HD) + hIdx * HD + d; wt = qw; }
  else           { p = kb + (size_t)s * (NKV * HD) + (hIdx - NH) * HD + d; wt = kw; }

  const float v = bf2f(*p);
  float ss = v * v;
  for (int off = 32; off; off >>= 1) ss += __shfl_down(ss, off);
  __shared__ float red[2];
  __shared__ float xs[128];
  if ((d & 63) == 0) red[d >> 6] = ss;
  __syncthreads();
  const float tot = red[0] + red[1];
  const float r   = rsqrtf(tot * (1.f / 128.f) + 1e-6f);
  const float xn  = v * r * wt[d];
  xs[d] = xn;
  __syncthreads();
  const float rot = (d < 64) ? -xs[d + 64] : xs[d - 64];
  float o = xn * cosb[s * HD + d] + rot * sinb[s * HD + d];
  if (hIdx < NH) o *= SCALE;  // fold softmax scale into q
  *p = f2bf(o);
}

// ---------------------------------------------------------------------------
// K3: causal flash attention, MFMA. 4 waves/block, (head, 64 q-rows)/block,
// 16 q-rows/wave. Fixed-max softmax (m=0): post-RMSNorm scores are bounded
// (|s|*scale <= ~25 by Cauchy-Schwarz), so exp() cannot overflow fp32 and
// the running-max machinery + O rescale is deleted. l-reduction deferred out
// of the kt loop. LDS: ks 16K + vt 16K + Ps 9K = 41.2 KB -> 3 blocks/CU.
// ---------------------------------------------------------------------------
#define PSTR 72  // P row stride (shorts)

__global__ __launch_bounds__(256)
void attn_mfma(const unsigned short* __restrict__ qB,
               const unsigned short* __restrict__ kB,
               const unsigned short* __restrict__ vT,
               unsigned short* __restrict__ oB) {
  __shared__ unsigned short ks[64 * 128];   // [key][d] dense
  __shared__ unsigned short vt[128 * 64];   // [d][key] dense
  __shared__ unsigned short Ps[4 * 16 * PSTR];

  const int t    = threadIdx.x;
  const int lane = t & 63;
  const int w    = t >> 6;
  const int qt   = (gridDim.x - 1) - blockIdx.x;  // heavy tiles first
  const int h    = blockIdx.y;
  const int kvh  = h >> 2;
  const int l15  = lane & 15;
  const int qd   = lane >> 4;

  // preload Q A-fragments (q pre-scaled by 1/sqrt(d) in norm_rope)
  short8 qf[4];
  {
    const unsigned short* qp =
        qB + (size_t)(qt * 64 + w * 16 + l15) * (NH * HD) + h * HD + qd * 8;
#pragma unroll
    for (int s = 0; s < 4; ++s) qf[s] = *(const short8*)(qp + s * 32);
  }

  f32x4 O[8];
#pragma unroll
  for (int nt = 0; nt < 8; ++nt)
#pragma unroll
    for (int e = 0; e < 4; ++e) O[nt][e] = 0.f;
  float l_i[4] = {0.f, 0.f, 0.f, 0.f};  // per-lane partial row sums

  unsigned short* Pw = Ps + w * (16 * PSTR);

  for (int kt = 0; kt <= qt; ++kt) {
    // ---- stage K-tile (64x128) and V^T-tile (128x64), dense, 16B DMA
#pragma unroll
    for (int c = 0; c < 4; ++c) {
      const int chunk = w * 4 + c;
      const int krow  = chunk * 4 + (lane >> 4);
      const unsigned short* gk = kB + (size_t)(kt * 64 + krow) * (NKV * HD) +
                                 kvh * HD + (lane & 15) * 8;
      __builtin_amdgcn_global_load_lds(
          (const __attribute__((address_space(1))) void*)gk,
          (__attribute__((address_space(3))) void*)(ks + chunk * 512), 16, 0, 0);
      const int drow = chunk * 8 + (lane >> 3);
      const unsigned short* gv = vT + (size_t)(kvh * HD + drow) * S_LEN +
                                 kt * 64 + (lane & 7) * 8;
      __builtin_amdgcn_global_load_lds(
          (const __attribute__((address_space(1))) void*)gv,
          (__attribute__((address_space(3))) void*)(vt + chunk * 512), 16, 0, 0);
    }
    asm volatile("s_waitcnt vmcnt(0)" ::: "memory");
    __syncthreads();

    // ---- QK^T
    f32x4 S[4];
#pragma unroll
    for (int ct = 0; ct < 4; ++ct) {
#pragma unroll
      for (int e = 0; e < 4; ++e) S[ct][e] = 0.f;
#pragma unroll
      for (int s = 0; s < 4; ++s) {
        const short8 kf =
            *(const short8*)(ks + (ct * 16 + l15) * 128 + s * 32 + qd * 8);
        S[ct] = __builtin_amdgcn_mfma_f32_16x16x32_bf16(qf[s], kf, S[ct], 0, 0, 0);
      }
    }

    // ---- causal mask (diagonal tile only; wave-uniform branch)
    if (kt == qt) {
#pragma unroll
      for (int ct = 0; ct < 4; ++ct)
#pragma unroll
        for (int i = 0; i < 4; ++i) {
          const int rloc = w * 16 + qd * 4 + i;
          const int cloc = ct * 16 + l15;
          if (cloc > rloc) S[ct][i] = -1e30f;
        }
    }

    // ---- P = exp(S), accumulate per-lane l, write P to per-wave LDS
#pragma unroll
    for (int ct = 0; ct < 4; ++ct)
#pragma unroll
      for (int i = 0; i < 4; ++i) {
        const float e = __expf(S[ct][i]);
        l_i[i] += e;
        Pw[(qd * 4 + i) * PSTR + ct * 16 + l15] = f2bf(e);
      }

    // ---- PV: O += P(16x64) * V(64x128)
    {
      const short8 pf0 = *(const short8*)(Pw + l15 * PSTR + qd * 8);
      const short8 pf1 = *(const short8*)(Pw + l15 * PSTR + 32 + qd * 8);
#pragma unroll
      for (int nt = 0; nt < 8; ++nt) {
        const short8 vf0 = *(const short8*)(vt + (nt * 16 + l15) * 64 + qd * 8);
        O[nt] = __builtin_amdgcn_mfma_f32_16x16x32_bf16(pf0, vf0, O[nt], 0, 0, 0);
        const short8 vf1 =
            *(const short8*)(vt + (nt * 16 + l15) * 64 + 32 + qd * 8);
        O[nt] = __builtin_amdgcn_mfma_f32_16x16x32_bf16(pf1, vf1, O[nt], 0, 0, 0);
      }
    }
    __syncthreads();  // protect ks/vt/Ps before next tile's staging
  }

  // ---- deferred l reduction (16-lane butterfly), then scaled store
  float linv[4];
#pragma unroll
  for (int i = 0; i < 4; ++i) {
    float s = l_i[i];
#pragma unroll
    for (int off = 1; off < 16; off <<= 1) s += __shfl_xor(s, off);
    linv[i] = 1.f / s;
  }
#pragma unroll
  for (int nt = 0; nt < 8; ++nt)
#pragma unroll
    for (int i = 0; i < 4; ++i) {
      const size_t row = (size_t)(qt * 64 + w * 16 + qd * 4 + i);
      oB[row * (NH * HD) + h * HD + nt * 16 + l15] = f2bf(O[nt][i] * linv[i]);
    }
}

// ---------------------------------------------------------------------------
extern "C" void kernel_launch(void* const* d_in, const int* in_sizes, int n_in,
                              void* d_out, int out_size, void* d_ws, size_t ws_size,
                              hipStream_t stream) {
  const float* x    = (const float*)d_in[0];
  const float* cosb = (const float*)d_in[1];
  const float* sinb = (const float*)d_in[2];
  const float* wq   = (const float*)d_in[3];
  const float* wk   = (const float*)d_in[4];
  const float* wv   = (const float*)d_in[5];
  const float* wo   = (const float*)d_in[6];
  const float* qnw  = (const float*)d_in[7];
  const float* knw  = (const float*)d_in[8];

  unsigned short* q     = (unsigned short*)d_ws;            // 2048*4096
  unsigned short* k     = q + (size_t)S_LEN * DIM;          // 2048*1024
  unsigned short* vT    = k + (size_t)S_LEN * NKV * HD;     // 1024*2048
  unsigned short* att   = vT + (size_t)NKV * HD * S_LEN;    // 2048*4096
  unsigned short* xb    = att + (size_t)S_LEN * DIM;        // 2048*4096
  unsigned short* wqkvb = xb + (size_t)S_LEN * DIM;         // 6144*4096
  unsigned short* wob   = wqkvb + (size_t)6144 * DIM;       // 4096*4096

  // K0: convert fp32 inputs to bf16 (x, wq|wk|wv, wo)
  cvt_all<<<dim3(24576), dim3(256), 0, stream>>>(x, wq, wk, wv, wo, xb, wqkvb,
                                                 wob);
  // K1: QKV projection, N = 6144 -> 48 col tiles (V stored transposed)
  gemm16<1, unsigned short>
      <<<dim3(48, 16), dim3(256), 0, stream>>>(xb, wqkvb, q, k, vT, DIM);
  // K2: RMSNorm + RoPE
  norm_rope<<<dim3(NH + NKV, S_LEN), dim3(128), 0, stream>>>(q, k, cosb, sinb,
                                                             qnw, knw);
  // K3: causal MFMA attention
  attn_mfma<<<dim3(S_LEN / 64, NH), dim3(256), 0, stream>>>(q, k, vT, att);
  // K4: output projection, N = 4096 -> 32 col tiles
  gemm16<0, float>
      <<<dim3(32, 16), dim3(256), 0, stream>>>(att, wob, (float*)d_out,
                                               nullptr, nullptr, DIM);
}

// Round 5
// 568.385 us; speedup vs baseline: 3.6041x; 1.3343x over previous
//
#include <hip/hip_runtime.h>

// ---------------------------------------------------------------------------
// Qwen3VL text-attention block. IO fp32; internal bf16 MFMA + fp32 accum.
//   K0: fp32 -> bf16 streaming convert of x, [wq;wk;wv], wo
//   K1: fused QKV projection GEMM (bf16, global_load_lds; V written TRANSPOSED)
//   K2: per-head RMSNorm + RoPE (softmax scale folded into q)
//   K3: causal flash attention, MFMA QK^T + PV, fixed-max softmax
//   K4: output projection GEMM (bf16 A/B -> fp32 d_out)
// All MFMA LDS tiles use an XOR granule swizzle:
//   slot(row, kg) = row*G + (kg ^ (row & (G-1)))   (granule = 8 bf16 = 16 B)
// so fragment reads spread the 16 l15-lanes over all bank groups (2-way max,
// free per m136) while global_load_lds staging stays fully coalesced (the
// swizzle only permutes granules within a row segment).
// ---------------------------------------------------------------------------

#define S_LEN 2048
#define DIM 4096
#define NH 32
#define NKV 8
#define HD 128
#define SCALE 0.08838834764831845f  // 1/sqrt(128)

typedef __attribute__((ext_vector_type(8))) short short8;
typedef __attribute__((ext_vector_type(4))) float f32x4;

__device__ __forceinline__ float bf2f(unsigned short u) {
  union { unsigned i; float f; } c; c.i = ((unsigned)u) << 16; return c.f;
}
__device__ __forceinline__ unsigned short f2bf(float f) {
  union { float f; unsigned u; } c; c.f = f;
  return (unsigned short)((c.u + 0x7fffu + ((c.u >> 16) & 1u)) >> 16);  // RNE
}
__device__ __forceinline__ void cvt8(const float* __restrict__ g,
                                     unsigned short* __restrict__ d) {
  const float4 a = *(const float4*)g;
  const float4 b = *(const float4*)(g + 4);
  short8 p;
  p[0] = (short)f2bf(a.x); p[1] = (short)f2bf(a.y);
  p[2] = (short)f2bf(a.z); p[3] = (short)f2bf(a.w);
  p[4] = (short)f2bf(b.x); p[5] = (short)f2bf(b.y);
  p[6] = (short)f2bf(b.z); p[7] = (short)f2bf(b.w);
  *(short8*)d = p;
}
__device__ __forceinline__ void storeC(float* p, float v) { *p = v; }
__device__ __forceinline__ void storeC(unsigned short* p, float v) { *p = f2bf(v); }

// ---------------------------------------------------------------------------
// K0: fp32 -> bf16 convert. One thread per 8-elem granule.
// ---------------------------------------------------------------------------
#define G_X   1048576u
#define G_WQ  2097152u
#define G_WK   524288u
#define G_WV   524288u
#define G_QKV (G_WQ + G_WK + G_WV)

__global__ __launch_bounds__(256)
void cvt_all(const float* __restrict__ x,  const float* __restrict__ wq,
             const float* __restrict__ wk, const float* __restrict__ wv,
             const float* __restrict__ wo,
             unsigned short* __restrict__ xb,
             unsigned short* __restrict__ wqkvb,
             unsigned short* __restrict__ wob) {
  const size_t g = (size_t)blockIdx.x * 256 + threadIdx.x;
  if (g < G_X) {
    cvt8(x + g * 8, xb + g * 8);
  } else if (g < G_X + G_QKV) {
    const size_t o = g - G_X;
    const float* s = (o < G_WQ) ? wq + o * 8
                   : (o < G_WQ + G_WK) ? wk + (o - G_WQ) * 8
                                       : wv + (o - G_WQ - G_WK) * 8;
    cvt8(s, wqkvb + o * 8);
  } else {
    const size_t o = g - (G_X + G_QKV);
    cvt8(wo + o * 8, wob + o * 8);
  }
}

// ---------------------------------------------------------------------------
// K1/K4: bf16 GEMM, C = A(MxK) @ B^T. 128x128 tile, BK=64, global_load_lds
// staging, 4 waves x (4x4) 16x16x32 MFMA. LDS rows (64 k = 8 granules)
// XOR-swizzled with G=8.
// ---------------------------------------------------------------------------
template <int QKV, typename TC>
__global__ __launch_bounds__(256)
void gemm16(const unsigned short* __restrict__ A,
            const unsigned short* __restrict__ B,
            TC* __restrict__ C0,
            unsigned short* __restrict__ Ck,
            unsigned short* __restrict__ Cv, int K) {
  __shared__ unsigned short lsA[128 * 64];
  __shared__ unsigned short lsB[128 * 64];

  const int t    = threadIdx.x;
  const int lane = t & 63;
  const int w    = t >> 6;
  const int m0   = blockIdx.y * 128;
  const int n0   = blockIdx.x * 128;

  f32x4 acc[4][4];
#pragma unroll
  for (int a = 0; a < 4; ++a)
#pragma unroll
    for (int b = 0; b < 4; ++b)
#pragma unroll
      for (int e = 0; e < 4; ++e) acc[a][b][e] = 0.f;

  const int l15  = lane & 15;
  const int qd   = lane >> 4;
  const int wr   = w >> 1, wc = w & 1;
  const int sr8  = lane >> 3;                       // staging row in 8-chunk
  const int skg  = (lane & 7) ^ sr8;                // swizzled staging granule
  const int l7   = l15 & 7;

  const int nkb = K >> 6;
  for (int kb = 0; kb < nkb; ++kb) {
    const int k0 = kb << 6;
#pragma unroll
    for (int c = 0; c < 4; ++c) {
      const int chunk = c * 4 + w;         // wave-uniform
      const int row   = chunk * 8 + sr8;
      const unsigned short* ga = A + (size_t)(m0 + row) * K + k0 + skg * 8;
      const unsigned short* gb = B + (size_t)(n0 + row) * K + k0 + skg * 8;
      __builtin_amdgcn_global_load_lds(
          (const __attribute__((address_space(1))) void*)ga,
          (__attribute__((address_space(3))) void*)(lsA + chunk * 512), 16, 0, 0);
      __builtin_amdgcn_global_load_lds(
          (const __attribute__((address_space(1))) void*)gb,
          (__attribute__((address_space(3))) void*)(lsB + chunk * 512), 16, 0, 0);
    }
    asm volatile("s_waitcnt vmcnt(0)" ::: "memory");
    __syncthreads();

#pragma unroll
    for (int half = 0; half < 2; ++half) {
      const int kg = (half * 4 + qd) ^ l7;  // swizzled read granule
      short8 af[4], bf[4];
#pragma unroll
      for (int mi = 0; mi < 4; ++mi)
        af[mi] = *(const short8*)(lsA + (wr * 64 + mi * 16 + l15) * 64 + kg * 8);
#pragma unroll
      for (int ni = 0; ni < 4; ++ni)
        bf[ni] = *(const short8*)(lsB + (wc * 64 + ni * 16 + l15) * 64 + kg * 8);
#pragma unroll
      for (int mi = 0; mi < 4; ++mi)
#pragma unroll
        for (int ni = 0; ni < 4; ++ni)
          acc[mi][ni] = __builtin_amdgcn_mfma_f32_16x16x32_bf16(
              af[mi], bf[ni], acc[mi][ni], 0, 0, 0);
    }
    __syncthreads();
  }

  // epilogue: C/D layout col=lane&15, row=quad*4+reg
#pragma unroll
  for (int mi = 0; mi < 4; ++mi)
#pragma unroll
    for (int i = 0; i < 4; ++i) {
      const int grow = m0 + wr * 64 + mi * 16 + qd * 4 + i;
#pragma unroll
      for (int ni = 0; ni < 4; ++ni) {
        const int gcol = n0 + wc * 64 + ni * 16 + l15;
        if (QKV) {
          if (n0 < 4096)
            storeC((unsigned short*)C0 + (size_t)grow * 4096 + gcol,
                   acc[mi][ni][i]);
          else if (n0 < 5120)
            Ck[(size_t)grow * 1024 + (gcol - 4096)] = f2bf(acc[mi][ni][i]);
          else  // V transposed: vT[d][token]
            Cv[(size_t)(gcol - 5120) * S_LEN + grow] = f2bf(acc[mi][ni][i]);
        } else {
          storeC(C0 + (size_t)grow * 4096 + gcol, acc[mi][ni][i]);
        }
      }
    }
}

// ---------------------------------------------------------------------------
// K2: RMSNorm (per head, 128 elems) + RoPE, in place on bf16 q and k.
// ---------------------------------------------------------------------------
__global__ __launch_bounds__(128)
void norm_rope(unsigned short* __restrict__ qb, unsigned short* __restrict__ kb,
               const float* __restrict__ cosb, const float* __restrict__ sinb,
               const float* __restrict__ qw, const float* __restrict__ kw) {
  const int hIdx = blockIdx.x;
  const int s    = blockIdx.y;
  const int d    = threadIdx.x;

  unsigned short* p; const float* wt;
  if (hIdx < NH) { p = qb + (size_t)s * (NH * HD) + hIdx * HD + d; wt = qw; }
  else           { p = kb + (size_t)s * (NKV * HD) + (hIdx - NH) * HD + d; wt = kw; }

  const float v = bf2f(*p);
  float ss = v * v;
  for (int off = 32; off; off >>= 1) ss += __shfl_down(ss, off);
  __shared__ float red[2];
  __shared__ float xs[128];
  if ((d & 63) == 0) red[d >> 6] = ss;
  __syncthreads();
  const float tot = red[0] + red[1];
  const float r   = rsqrtf(tot * (1.f / 128.f) + 1e-6f);
  const float xn  = v * r * wt[d];
  xs[d] = xn;
  __syncthreads();
  const float rot = (d < 64) ? -xs[d + 64] : xs[d - 64];
  float o = xn * cosb[s * HD + d] + rot * sinb[s * HD + d];
  if (hIdx < NH) o *= SCALE;  // fold softmax scale into q
  *p = f2bf(o);
}

// ---------------------------------------------------------------------------
// K3: causal flash attention, MFMA. 4 waves/block, (head, 64 q-rows)/block.
// ks: [key][dgran^key&15] (G=16 swizzle); vt: [d][kgran^d&7] (G=8 swizzle).
// Fixed-max softmax (post-RMSNorm scores bounded), deferred l-reduction.
// LDS: 16K + 16K + 9K = 41.2 KB.
// ---------------------------------------------------------------------------
#define PSTR 72  // P row stride (shorts)

__global__ __launch_bounds__(256)
void attn_mfma(const unsigned short* __restrict__ qB,
               const unsigned short* __restrict__ kB,
               const unsigned short* __restrict__ vT,
               unsigned short* __restrict__ oB) {
  __shared__ unsigned short ks[64 * 128];   // [key][16 granules, swizzled]
  __shared__ unsigned short vt[128 * 64];   // [d][8 granules, swizzled]
  __shared__ unsigned short Ps[4 * 16 * PSTR];

  const int t    = threadIdx.x;
  const int lane = t & 63;
  const int w    = t >> 6;
  const int qt   = (gridDim.x - 1) - blockIdx.x;  // heavy tiles first
  const int h    = blockIdx.y;
  const int kvh  = h >> 2;
  const int l15  = lane & 15;
  const int qd   = lane >> 4;
  const int l7   = l15 & 7;

  // staging index helpers
  const int kr16 = lane >> 4;                 // K staging: row within 4-chunk
  const int vr8  = lane >> 3;                 // V staging: row within 8-chunk
  const int vkg  = (lane & 7) ^ (vr8 & 7);    // V staging swizzled granule

  // preload Q A-fragments (q pre-scaled by 1/sqrt(d) in norm_rope)
  short8 qf[4];
  {
    const unsigned short* qp =
        qB + (size_t)(qt * 64 + w * 16 + l15) * (NH * HD) + h * HD + qd * 8;
#pragma unroll
    for (int s = 0; s < 4; ++s) qf[s] = *(const short8*)(qp + s * 32);
  }

  f32x4 O[8];
#pragma unroll
  for (int nt = 0; nt < 8; ++nt)
#pragma unroll
    for (int e = 0; e < 4; ++e) O[nt][e] = 0.f;
  float l_i[4] = {0.f, 0.f, 0.f, 0.f};

  unsigned short* Pw = Ps + w * (16 * PSTR);

  for (int kt = 0; kt <= qt; ++kt) {
    // ---- stage K-tile (64x128) and V^T-tile (128x64), swizzled, 16B DMA
#pragma unroll
    for (int c = 0; c < 4; ++c) {
      const int chunk = w * 4 + c;
      // K: key = chunk*4 + kr16; dgran = (lane&15) ^ (key&15)
      const int key = chunk * 4 + kr16;
      const int dg  = (lane & 15) ^ (key & 15);
      const unsigned short* gk = kB + (size_t)(kt * 64 + key) * (NKV * HD) +
                                 kvh * HD + dg * 8;
      __builtin_amdgcn_global_load_lds(
          (const __attribute__((address_space(1))) void*)gk,
          (__attribute__((address_space(3))) void*)(ks + chunk * 512), 16, 0, 0);
      // V: d = chunk*8 + vr8; kgran = vkg
      const int dv = chunk * 8 + vr8;
      const unsigned short* gv = vT + (size_t)(kvh * HD + dv) * S_LEN +
                                 kt * 64 + vkg * 8;
      __builtin_amdgcn_global_load_lds(
          (const __attribute__((address_space(1))) void*)gv,
          (__attribute__((address_space(3))) void*)(vt + chunk * 512), 16, 0, 0);
    }
    asm volatile("s_waitcnt vmcnt(0)" ::: "memory");
    __syncthreads();

    // ---- QK^T
    f32x4 S[4];
#pragma unroll
    for (int ct = 0; ct < 4; ++ct) {
#pragma unroll
      for (int e = 0; e < 4; ++e) S[ct][e] = 0.f;
#pragma unroll
      for (int s = 0; s < 4; ++s) {
        const int kg = (s * 4 + qd) ^ l15;  // G=16 swizzle (key&15 = l15)
        const short8 kf =
            *(const short8*)(ks + (ct * 16 + l15) * 128 + kg * 8);
        S[ct] = __builtin_amdgcn_mfma_f32_16x16x32_bf16(qf[s], kf, S[ct], 0, 0, 0);
      }
    }

    // ---- causal mask (diagonal tile only)
    if (kt == qt) {
#pragma unroll
      for (int ct = 0; ct < 4; ++ct)
#pragma unroll
        for (int i = 0; i < 4; ++i) {
          const int rloc = w * 16 + qd * 4 + i;
          const int cloc = ct * 16 + l15;
          if (cloc > rloc) S[ct][i] = -1e30f;
        }
    }

    // ---- P = exp(S), accumulate per-lane l, write P to per-wave LDS
#pragma unroll
    for (int ct = 0; ct < 4; ++ct)
#pragma unroll
      for (int i = 0; i < 4; ++i) {
        const float e = __expf(S[ct][i]);
        l_i[i] += e;
        Pw[(qd * 4 + i) * PSTR + ct * 16 + l15] = f2bf(e);
      }

    // ---- PV: O += P(16x64) * V(64x128)
    {
      const short8 pf0 = *(const short8*)(Pw + l15 * PSTR + qd * 8);
      const short8 pf1 = *(const short8*)(Pw + l15 * PSTR + 32 + qd * 8);
#pragma unroll
      for (int nt = 0; nt < 8; ++nt) {
        const int kg0 = qd ^ l7;        // half 0, G=8 swizzle (d&7 = l7)
        const int kg1 = (4 + qd) ^ l7;  // half 1
        const short8 vf0 =
            *(const short8*)(vt + (nt * 16 + l15) * 64 + kg0 * 8);
        O[nt] = __builtin_amdgcn_mfma_f32_16x16x32_bf16(pf0, vf0, O[nt], 0, 0, 0);
        const short8 vf1 =
            *(const short8*)(vt + (nt * 16 + l15) * 64 + kg1 * 8);
        O[nt] = __builtin_amdgcn_mfma_f32_16x16x32_bf16(pf1, vf1, O[nt], 0, 0, 0);
      }
    }
    __syncthreads();  // protect ks/vt before next tile's staging
  }

  // ---- deferred l reduction (16-lane butterfly), then scaled store
  float linv[4];
#pragma unroll
  for (int i = 0; i < 4; ++i) {
    float s = l_i[i];
#pragma unroll
    for (int off = 1; off < 16; off <<= 1) s += __shfl_xor(s, off);
    linv[i] = 1.f / s;
  }
#pragma unroll
  for (int nt = 0; nt < 8; ++nt)
#pragma unroll
    for (int i = 0; i < 4; ++i) {
      const size_t row = (size_t)(qt * 64 + w * 16 + qd * 4 + i);
      oB[row * (NH * HD) + h * HD + nt * 16 + l15] = f2bf(O[nt][i] * linv[i]);
    }
}

// ---------------------------------------------------------------------------
extern "C" void kernel_launch(void* const* d_in, const int* in_sizes, int n_in,
                              void* d_out, int out_size, void* d_ws, size_t ws_size,
                              hipStream_t stream) {
  const float* x    = (const float*)d_in[0];
  const float* cosb = (const float*)d_in[1];
  const float* sinb = (const float*)d_in[2];
  const float* wq   = (const float*)d_in[3];
  const float* wk   = (const float*)d_in[4];
  const float* wv   = (const float*)d_in[5];
  const float* wo   = (const float*)d_in[6];
  const float* qnw  = (const float*)d_in[7];
  const float* knw  = (const float*)d_in[8];

  unsigned short* q     = (unsigned short*)d_ws;            // 2048*4096
  unsigned short* k     = q + (size_t)S_LEN * DIM;          // 2048*1024
  unsigned short* vT    = k + (size_t)S_LEN * NKV * HD;     // 1024*2048
  unsigned short* att   = vT + (size_t)NKV * HD * S_LEN;    // 2048*4096
  unsigned short* xb    = att + (size_t)S_LEN * DIM;        // 2048*4096
  unsigned short* wqkvb = xb + (size_t)S_LEN * DIM;         // 6144*4096
  unsigned short* wob   = wqkvb + (size_t)6144 * DIM;       // 4096*4096

  // K0: convert fp32 inputs to bf16
  cvt_all<<<dim3(24576), dim3(256), 0, stream>>>(x, wq, wk, wv, wo, xb, wqkvb,
                                                 wob);
  // K1: QKV projection, N = 6144 -> 48 col tiles (V stored transposed)
  gemm16<1, unsigned short>
      <<<dim3(48, 16), dim3(256), 0, stream>>>(xb, wqkvb, q, k, vT, DIM);
  // K2: RMSNorm + RoPE
  norm_rope<<<dim3(NH + NKV, S_LEN), dim3(128), 0, stream>>>(q, k, cosb, sinb,
                                                             qnw, knw);
  // K3: causal MFMA attention
  attn_mfma<<<dim3(S_LEN / 64, NH), dim3(256), 0, stream>>>(q, k, vT, att);
  // K4: output projection, N = 4096 -> 32 col tiles
  gemm16<0, float>
      <<<dim3(32, 16), dim3(256), 0, stream>>>(att, wob, (float*)d_out,
                                               nullptr, nullptr, DIM);
}